// Round 19
// baseline (17.297 us; speedup 1.0000x reference)
//
#include <hip/hip_runtime.h>
#include <math.h>
#include <utility>

#define NPTS 262144
#define K 32
#define D 16
#define R 160            // 136 triangle + 16 linear + 8 pad -> 10 MFMA K-steps
#define NSTEPS 10
#define NBLK 512         // 4 waves/block, 4 tiles/wave -> 8192 tiles
#define LROW 352         // 20 data granules + 2 pad granules per theta row
#define IMG_BYTES 11264  // 32 rows * 352 B, single fp16 theta image
#define LCSLOT 148       // pad slot: lc_hi; slot 149: lc_lo; phi there == 1.0

typedef _Float16 f16x2 __attribute__((ext_vector_type(2)));
typedef _Float16 f16x8 __attribute__((ext_vector_type(8)));
typedef __attribute__((ext_vector_type(16))) float f32x16;
typedef __attribute__((ext_vector_type(4))) int int4v;

// ---- compile-time dual-cell table (round-12 pairing) -------------------
struct PTab {
  short dty[40], cu0[40], cv0[40], cu1[40], cv1[40];
  short pd[160], pf[160];
  constexpr PTab() : dty{}, cu0{}, cv0{}, cu1{}, cv1{}, pd{}, pf{} {
    int n = 0;
    for (int j = 0; j < 8; ++j)                     // 28 ROW duals
      for (int i = 0; i < j; ++i) {
        dty[n]=0; cu0[n]=(short)(2*i); cv0[n]=(short)j;
        cu1[n]=(short)(2*i+1); cv1[n]=(short)j; ++n;
      }
    for (int t = 0; t < 4; ++t) {                   // 4 ROWX duals
      dty[n]=1; cu0[n]=(short)(4*t); cv0[n]=(short)(2*t);
      cu1[n]=(short)(4*t+2); cv1[n]=(short)(2*t+1); ++n;
    }
    for (int t = 0; t < 2; ++t) {                   // 2 DIAG duals
      dty[n]=2; cu0[n]=(short)(2*t); cu1[n]=(short)(2*t+1);
      cv0[n]=0; cv1[n]=0; ++n;
    }
    for (int t = 0; t < 4; ++t) {                   // 4 LIN duals
      dty[n]=3; cu0[n]=(short)(2*t); cu1[n]=(short)(2*t+1);
      cv0[n]=0; cv1[n]=0; ++n;
    }
    for (int t = 0; t < 2; ++t) {                   // 2 PAD duals (cells 38,39)
      dty[n]=4; cu0[n]=0; cu1[n]=0; cv0[n]=0; cv1[n]=0; ++n;
    }
    for (int c = 0; c < 40; ++c) {
      int S = c / 4, a = c % 4;
      for (int kh = 0; kh < 2; ++kh)
        for (int e = 0; e < 2; ++e) {
          int q = S*16 + kh*8 + a*2 + e;
          int ty = dty[c];
          int u = kh ? cu1[c] : cu0[c];
          int v = kh ? cv1[c] : cv0[c];
          if (ty == 0 || ty == 1) { pd[q] = (short)u; pf[q] = (short)(2*v + e); }
          else if (ty == 2) { int s = u; pd[q] = pf[q] = (short)(4*s + 1 + 2*e); }
          else if (ty == 3) { pd[q] = 16; pf[q] = (short)(2*u + e); }
          else { pd[q] = 17; pf[q] = 0; }
        }
    }
  }
};
static constexpr PTab TAB{};

// ---------------- prep kernel: one block per component k ----------------
__global__ __launch_bounds__(256) void gm_prep_kernel(
    const float* __restrict__ m_w,
    const float* __restrict__ l_fac,
    const float* __restrict__ p_logits,
    char* __restrict__ thimg)
{
  const int k = blockIdx.x;
  const int tid = threadIdx.x;
  const int r = tid >> 4, c = tid & 15;
  __shared__ float A[D][D];
  __shared__ float L[D][D];
  __shared__ float S[2][D][D];
  __shared__ float Gd[D];
  __shared__ float piv[D];
  __shared__ float ld[D];
  __shared__ float sm[K];
  __shared__ float sme[K];
  __shared__ float smax;
  __shared__ float lc_sh;
  const float LOG2E = 1.4426950408889634f;

  A[r][c] = l_fac[k * D * D + r * D + c];
  if (tid < K) sm[tid] = p_logits[tid];
  __syncthreads();

  {
    float s = 0.f;
    #pragma unroll
    for (int e = 0; e < D; ++e) s += A[r][e] * A[c][e];
    s *= (1.0f / D);
    L[r][c] = s;
    S[0][r][c] = s;
  }
  if (tid == 0) {
    float mx = -1e30f;
    for (int i = 0; i < K; ++i) mx = fmaxf(mx, sm[i]);
    smax = mx;
  }
  __syncthreads();

  if (tid < D) {
    float s = 0.f;
    #pragma unroll
    for (int f = 0; f < D; ++f) s += L[tid][f] * m_w[k * D + f];
    Gd[tid] = s;
  }

  int cb = 0;
  for (int j = 0; j < 15; ++j) {
    float pj = S[cb][j][j];
    float a = S[cb][r][j], b = S[cb][c][j], v = S[cb][r][c];
    if (tid == 0) piv[j] = pj;
    if (r > j && c > j) S[cb ^ 1][r][c] = v - a * b / pj;
    cb ^= 1;
    __syncthreads();
  }
  if (tid == 0) piv[15] = S[cb][15][15];
  __syncthreads();

  // parallel transcendentals
  if (tid < D) ld[tid] = logf(piv[tid]);
  else if (tid >= 32 && tid < 32 + K) sme[tid - 32] = expf(sm[tid - 32] - smax);
  __syncthreads();

  if (tid == 0) {
    float z = 0.f;
    for (int i = 0; i < K; ++i) z += sme[i];
    float logp = sm[k] - smax - logf(z);
    float logdet_sqrt = 0.f;
    for (int j = 0; j < D; ++j) logdet_sqrt += ld[j];
    logdet_sqrt *= 0.5f;
    float cc = 0.f;
    for (int d2 = 0; d2 < D; ++d2) cc += m_w[k * D + d2] * Gd[d2];
    float lc = logp - 14.703016531274763f + logdet_sqrt - 0.5f * cc;
    lc_sh = LOG2E * lc;
  }
  __syncthreads();

  // theta -> fp16 (RNE), pre-swizzled single image; lc hi/lo at 148/149
  for (int q = tid; q < R; q += 256) {
    int d = TAB.pd[q], f = TAB.pf[q];
    float th;
    if (q == LCSLOT) th = lc_sh;
    else if (q == LCSLOT + 1) th = lc_sh - (float)((_Float16)lc_sh);
    else if (d == 17) th = 0.f;
    else if (d == 16) th = LOG2E * Gd[f];
    else th = ((d == f) ? -0.5f : -1.0f) * LOG2E * L[d][f];
    _Float16 h = (_Float16)th;           // RNE
    int m = q >> 3, e = q & 7;
    int sg = (k & 7) ^ (k >> 3);
    int phys = (m < 16) ? (m ^ sg) : (16 + ((m - 16) ^ (sg & 3)));
    size_t off = (size_t)k * LROW + (size_t)phys * 16 + (size_t)e * 2;
    *(unsigned short*)(thimg + off) = __builtin_bit_cast(unsigned short, h);
  }
}

__device__ __forceinline__ int bcst(f16x2 v) { return __builtin_bit_cast(int, v); }
__device__ __forceinline__ f16x2 fint(int v) { return __builtin_bit_cast(f16x2, v); }

// one fp16x2 phi dword for dual C (hi-only)
template<int C>
__device__ __forceinline__ int dualphi_h(int kh,
    const f16x2 (&xh)[8], const f16x2 (&su_h)[8], const f16x2 (&dgh)[4])
{
  constexpr int ty = TAB.dty[C];
  constexpr int U0 = TAB.cu0[C], V0 = TAB.cv0[C];
  constexpr int U1 = TAB.cu1[C], V1 = TAB.cv1[C];
  if constexpr (ty == 4) {
    if constexpr (C == 38) return 0x3C003C00;    // (1.0,1.0): lc hi+lo slots
    else return 0;
  } else if constexpr (ty == 3) {                 // linear: phi = x
    return kh ? bcst(xh[U1]) : bcst(xh[U0]);
  } else if constexpr (ty == 2) {                 // odd diagonals: x_d^2
    f16x2 Dh = fint(kh ? bcst(dgh[U1]) : bcst(dgh[U0]));
    return bcst(Dh * Dh);
  } else if constexpr (ty == 1) {                 // ROWX: even-diag leftovers
    constexpr int T = U0 >> 2;
    f16x2 uh = fint(kh ? bcst(xh[2*T+1]) : bcst(xh[2*T]));
    f16x2 Uh = __builtin_shufflevector(uh, uh, 0, 0);
    f16x2 Vh = fint(kh ? bcst(xh[V1]) : bcst(xh[V0]));
    return bcst(Uh * Vh);
  } else {                                        // ROW: pre-selected splat
    constexpr int I = U0 >> 1;
    return bcst(su_h[I] * xh[V0]);                // V0==V1 for ROW
  }
}

// 1 MFMA per step (10 per tile)
template<int S>
__device__ __forceinline__ void do_step(int kh,
    const f16x2 (&xh)[8], const f16x2 (&su_h)[8], const f16x2 (&dgh)[4],
    const char* lthp, int base2, int sigh, f32x16& acc)
{
  int va;
  if constexpr (S < 8) va = base2 + ((S ^ sigh) << 5);
  else                 va = base2 + 256 + (((S - 8) ^ (sigh & 1)) << 5);
  int4v thv = *(const int4v*)(lthp + va);
  int4v hh = { dualphi_h<S*4+0>(kh, xh, su_h, dgh),
               dualphi_h<S*4+1>(kh, xh, su_h, dgh),
               dualphi_h<S*4+2>(kh, xh, su_h, dgh),
               dualphi_h<S*4+3>(kh, xh, su_h, dgh) };
  acc = __builtin_amdgcn_mfma_f32_32x32x16_f16(
      __builtin_bit_cast(f16x8, thv), __builtin_bit_cast(f16x8, hh), acc, 0, 0, 0);
}

template<int... Ss>
__device__ __forceinline__ void all_steps(std::integer_sequence<int, Ss...>,
    int kh, const f16x2 (&xh)[8], const f16x2 (&su_h)[8], const f16x2 (&dgh)[4],
    const char* lthp, int base2, int sigh, f32x16& acc)
{
  (do_step<Ss>(kh, xh, su_h, dgh, lthp, base2, sigh, acc), ...);
}

// per-tile pipeline; x -> fp16 via RNE
__device__ __forceinline__ void process_tile(
    const float4 (&xv)[4], int t, int lane, int p, int kh,
    const char* lthp, int base2, int sigh, float* __restrict__ out)
{
  float xs[16];
  xs[0]=xv[0].x; xs[1]=xv[0].y; xs[2]=xv[0].z; xs[3]=xv[0].w;
  xs[4]=xv[1].x; xs[5]=xv[1].y; xs[6]=xv[1].z; xs[7]=xv[1].w;
  xs[8]=xv[2].x; xs[9]=xv[2].y; xs[10]=xv[2].z; xs[11]=xv[2].w;
  xs[12]=xv[3].x; xs[13]=xv[3].y; xs[14]=xv[3].z; xs[15]=xv[3].w;

  f16x2 xh[8];
  #pragma unroll
  for (int i = 0; i < 8; ++i)
    xh[i] = f16x2{(_Float16)xs[2*i], (_Float16)xs[2*i+1]};   // RNE

  f16x2 su_h[8];
  #pragma unroll
  for (int i = 0; i < 8; ++i) {
    f16x2 lo = __builtin_shufflevector(xh[i], xh[i], 0, 0);
    f16x2 hi = __builtin_shufflevector(xh[i], xh[i], 1, 1);
    su_h[i] = fint(kh ? bcst(hi) : bcst(lo));
  }
  f16x2 dgh[4];
  #pragma unroll
  for (int s = 0; s < 4; ++s)
    dgh[s] = __builtin_shufflevector(xh[2*s], xh[2*s+1], 1, 3);

  f32x16 acc;
  #pragma unroll
  for (int i = 0; i < 16; ++i) acc[i] = 0.f;

  all_steps(std::make_integer_sequence<int, NSTEPS>{}, kh, xh, su_h, dgh,
            lthp, base2, sigh, acc);

  float e[16];
  #pragma unroll
  for (int i = 0; i < 16; ++i)
    e[i] = __builtin_amdgcn_exp2f(acc[i]);     // lc folded via slots 148/149
  float a0 = (e[0] + e[1]) + (e[2] + e[3]);
  float a1 = (e[4] + e[5]) + (e[6] + e[7]);
  float a2 = (e[8] + e[9]) + (e[10] + e[11]);
  float a3 = (e[12] + e[13]) + (e[14] + e[15]);
  float ss = (a0 + a1) + (a2 + a3);
  ss += __shfl_xor(ss, 32);
  if (lane < 32) out[(size_t)t * 32 + p] = ss;
}

// ---------------- density kernel: 512 blocks, 4 tiles/wave ----------------
// Hypothesis test (r18 post-mortem): per-dispatch fixed cost ~11us scales
// with block count (ramp + per-block startup). Halve blocks, 4 tiles/wave,
// all 4 x-loads in flight up-front (hide under staging+barrier). Register
// rotation with static indices only (rule #20). VGPR est ~115 < 128.
__global__ __launch_bounds__(256) void gm_mfma_kernel(
    const float* __restrict__ x,
    const char*  __restrict__ thimg,
    float* __restrict__ out)
{
  __shared__ __align__(16) char lth[IMG_BYTES];
  const int tid = threadIdx.x;
  const int lane = tid & 63;
  const int p = lane & 31;
  const int kh = lane >> 5;
  const int t0 = (blockIdx.x * 4 + (tid >> 6)) * 4;   // 4 tiles per wave

  // issue all 4 tiles' x loads first (16 dwordx4 in flight across staging)
  const float4* xq0 = (const float4*)(x + ((size_t)(t0 + 0) * 32 + p) * D);
  const float4* xq1 = (const float4*)(x + ((size_t)(t0 + 1) * 32 + p) * D);
  const float4* xq2 = (const float4*)(x + ((size_t)(t0 + 2) * 32 + p) * D);
  const float4* xq3 = (const float4*)(x + ((size_t)(t0 + 3) * 32 + p) * D);
  float4 c0[4], c1[4], c2[4], c3[4];
  #pragma unroll
  for (int i = 0; i < 4; ++i) {
    c0[i] = xq0[i]; c1[i] = xq1[i]; c2[i] = xq2[i]; c3[i] = xq3[i];
  }

  // stage theta image -> LDS, pure linear copy (pre-swizzled by prep)
  for (int i = tid; i < IMG_BYTES / 16; i += 256) {
    int4v v = *(const int4v*)(thimg + i * 16);
    *(int4v*)(lth + i * 16) = v;
  }
  __syncthreads();

  const int sig = (p & 7) ^ (p >> 3);
  const int base2 = p * LROW + ((kh ^ (sig & 1)) << 4);
  const int sigh = sig >> 1;

  #pragma unroll 1
  for (int tt = 0; tt < 4; ++tt) {
    process_tile(c0, t0 + tt, lane, p, kh, lth, base2, sigh, out);
    // static-index register rotation (rule #20: no runtime-indexed arrays)
    #pragma unroll
    for (int i = 0; i < 4; ++i) { c0[i] = c1[i]; c1[i] = c2[i]; c2[i] = c3[i]; }
  }
}

extern "C" void kernel_launch(void* const* d_in, const int* in_sizes, int n_in,
                              void* d_out, int out_size, void* d_ws, size_t ws_size,
                              hipStream_t stream) {
  const float* x        = (const float*)d_in[0];
  const float* m_w      = (const float*)d_in[1];
  const float* l_fac    = (const float*)d_in[2];
  const float* p_logits = (const float*)d_in[3];
  float* out = (float*)d_out;
  char* thimg = (char*)d_ws;   // IMG_BYTES pre-swizzled fp16 theta image

  gm_prep_kernel<<<K, 256, 0, stream>>>(m_w, l_fac, p_logits, thimg);
  gm_mfma_kernel<<<NBLK, 256, 0, stream>>>(x, thimg, out);
}

// Round 20
// 16.909 us; speedup vs baseline: 1.0229x; 1.0229x over previous
//
#include <hip/hip_runtime.h>
#include <math.h>
#include <utility>

#define NPTS 262144
#define K 32
#define D 16
#define R 160            // 136 triangle + 16 linear + 8 pad -> 10 MFMA K-steps
#define NSTEPS 10
#define NBLK 1024        // 4 waves/block, 2 tiles/wave -> 8192 tiles
#define LROW 352         // 20 data granules + 2 pad granules per theta row
#define IMG_BYTES 11264  // 32 rows * 352 B, single fp16 theta image
#define LCSLOT 148       // pad slot: lc_hi; slot 149: lc_lo; phi there == 1.0

typedef _Float16 f16x2 __attribute__((ext_vector_type(2)));
typedef _Float16 f16x8 __attribute__((ext_vector_type(8)));
typedef __attribute__((ext_vector_type(16))) float f32x16;
typedef __attribute__((ext_vector_type(4))) int int4v;

// ---- compile-time dual-cell table (round-12 pairing) -------------------
struct PTab {
  short dty[40], cu0[40], cv0[40], cu1[40], cv1[40];
  short pd[160], pf[160];
  constexpr PTab() : dty{}, cu0{}, cv0{}, cu1{}, cv1{}, pd{}, pf{} {
    int n = 0;
    for (int j = 0; j < 8; ++j)                     // 28 ROW duals
      for (int i = 0; i < j; ++i) {
        dty[n]=0; cu0[n]=(short)(2*i); cv0[n]=(short)j;
        cu1[n]=(short)(2*i+1); cv1[n]=(short)j; ++n;
      }
    for (int t = 0; t < 4; ++t) {                   // 4 ROWX duals
      dty[n]=1; cu0[n]=(short)(4*t); cv0[n]=(short)(2*t);
      cu1[n]=(short)(4*t+2); cv1[n]=(short)(2*t+1); ++n;
    }
    for (int t = 0; t < 2; ++t) {                   // 2 DIAG duals
      dty[n]=2; cu0[n]=(short)(2*t); cu1[n]=(short)(2*t+1);
      cv0[n]=0; cv1[n]=0; ++n;
    }
    for (int t = 0; t < 4; ++t) {                   // 4 LIN duals
      dty[n]=3; cu0[n]=(short)(2*t); cu1[n]=(short)(2*t+1);
      cv0[n]=0; cv1[n]=0; ++n;
    }
    for (int t = 0; t < 2; ++t) {                   // 2 PAD duals (cells 38,39)
      dty[n]=4; cu0[n]=0; cu1[n]=0; cv0[n]=0; cv1[n]=0; ++n;
    }
    for (int c = 0; c < 40; ++c) {
      int S = c / 4, a = c % 4;
      for (int kh = 0; kh < 2; ++kh)
        for (int e = 0; e < 2; ++e) {
          int q = S*16 + kh*8 + a*2 + e;
          int ty = dty[c];
          int u = kh ? cu1[c] : cu0[c];
          int v = kh ? cv1[c] : cv0[c];
          if (ty == 0 || ty == 1) { pd[q] = (short)u; pf[q] = (short)(2*v + e); }
          else if (ty == 2) { int s = u; pd[q] = pf[q] = (short)(4*s + 1 + 2*e); }
          else if (ty == 3) { pd[q] = 16; pf[q] = (short)(2*u + e); }
          else { pd[q] = 17; pf[q] = 0; }
        }
    }
  }
};
static constexpr PTab TAB{};

// ---------------- prep kernel: one block per component k ----------------
// Single pre-swizzled fp16 (RNE) theta image; lc carried exactly via pad
// slots 148 (hi) and 149 (lo residual), phi there == 1.0.
__global__ __launch_bounds__(256) void gm_prep_kernel(
    const float* __restrict__ m_w,
    const float* __restrict__ l_fac,
    const float* __restrict__ p_logits,
    char* __restrict__ thimg)
{
  const int k = blockIdx.x;
  const int tid = threadIdx.x;
  const int r = tid >> 4, c = tid & 15;
  __shared__ float A[D][D];
  __shared__ float L[D][D];
  __shared__ float S[2][D][D];
  __shared__ float Gd[D];
  __shared__ float piv[D];
  __shared__ float ld[D];
  __shared__ float sm[K];
  __shared__ float sme[K];
  __shared__ float smax;
  __shared__ float lc_sh;
  const float LOG2E = 1.4426950408889634f;

  A[r][c] = l_fac[k * D * D + r * D + c];
  if (tid < K) sm[tid] = p_logits[tid];
  __syncthreads();

  {
    float s = 0.f;
    #pragma unroll
    for (int e = 0; e < D; ++e) s += A[r][e] * A[c][e];
    s *= (1.0f / D);
    L[r][c] = s;
    S[0][r][c] = s;
  }
  if (tid == 0) {
    float mx = -1e30f;
    for (int i = 0; i < K; ++i) mx = fmaxf(mx, sm[i]);
    smax = mx;
  }
  __syncthreads();

  if (tid < D) {
    float s = 0.f;
    #pragma unroll
    for (int f = 0; f < D; ++f) s += L[tid][f] * m_w[k * D + f];
    Gd[tid] = s;
  }

  int cb = 0;
  for (int j = 0; j < 15; ++j) {
    float pj = S[cb][j][j];
    float a = S[cb][r][j], b = S[cb][c][j], v = S[cb][r][c];
    if (tid == 0) piv[j] = pj;
    if (r > j && c > j) S[cb ^ 1][r][c] = v - a * b / pj;
    cb ^= 1;
    __syncthreads();
  }
  if (tid == 0) piv[15] = S[cb][15][15];
  __syncthreads();

  // parallel transcendentals
  if (tid < D) ld[tid] = logf(piv[tid]);
  else if (tid >= 32 && tid < 32 + K) sme[tid - 32] = expf(sm[tid - 32] - smax);
  __syncthreads();

  if (tid == 0) {
    float z = 0.f;
    for (int i = 0; i < K; ++i) z += sme[i];
    float logp = sm[k] - smax - logf(z);
    float logdet_sqrt = 0.f;
    for (int j = 0; j < D; ++j) logdet_sqrt += ld[j];
    logdet_sqrt *= 0.5f;
    float cc = 0.f;
    for (int d2 = 0; d2 < D; ++d2) cc += m_w[k * D + d2] * Gd[d2];
    float lc = logp - 14.703016531274763f + logdet_sqrt - 0.5f * cc;
    lc_sh = LOG2E * lc;
  }
  __syncthreads();

  // theta -> fp16 (RNE), pre-swizzled single image; lc hi/lo at 148/149
  for (int q = tid; q < R; q += 256) {
    int d = TAB.pd[q], f = TAB.pf[q];
    float th;
    if (q == LCSLOT) th = lc_sh;
    else if (q == LCSLOT + 1) th = lc_sh - (float)((_Float16)lc_sh);
    else if (d == 17) th = 0.f;
    else if (d == 16) th = LOG2E * Gd[f];
    else th = ((d == f) ? -0.5f : -1.0f) * LOG2E * L[d][f];
    _Float16 h = (_Float16)th;           // RNE
    int m = q >> 3, e = q & 7;
    int sg = (k & 7) ^ (k >> 3);
    int phys = (m < 16) ? (m ^ sg) : (16 + ((m - 16) ^ (sg & 3)));
    size_t off = (size_t)k * LROW + (size_t)phys * 16 + (size_t)e * 2;
    *(unsigned short*)(thimg + off) = __builtin_bit_cast(unsigned short, h);
  }
}

__device__ __forceinline__ int bcst(f16x2 v) { return __builtin_bit_cast(int, v); }
__device__ __forceinline__ f16x2 fint(int v) { return __builtin_bit_cast(f16x2, v); }

// one fp16x2 phi dword for dual C (hi-only; cross term dropped)
template<int C>
__device__ __forceinline__ int dualphi_h(int kh,
    const f16x2 (&xh)[8], const f16x2 (&su_h)[8], const f16x2 (&dgh)[4])
{
  constexpr int ty = TAB.dty[C];
  constexpr int U0 = TAB.cu0[C], V0 = TAB.cv0[C];
  constexpr int U1 = TAB.cu1[C], V1 = TAB.cv1[C];
  if constexpr (ty == 4) {
    if constexpr (C == 38) return 0x3C003C00;    // (1.0,1.0): lc hi+lo slots
    else return 0;
  } else if constexpr (ty == 3) {                 // linear: phi = x
    return kh ? bcst(xh[U1]) : bcst(xh[U0]);
  } else if constexpr (ty == 2) {                 // odd diagonals: x_d^2
    f16x2 Dh = fint(kh ? bcst(dgh[U1]) : bcst(dgh[U0]));
    return bcst(Dh * Dh);
  } else if constexpr (ty == 1) {                 // ROWX: even-diag leftovers
    constexpr int T = U0 >> 2;
    f16x2 uh = fint(kh ? bcst(xh[2*T+1]) : bcst(xh[2*T]));
    f16x2 Uh = __builtin_shufflevector(uh, uh, 0, 0);
    f16x2 Vh = fint(kh ? bcst(xh[V1]) : bcst(xh[V0]));
    return bcst(Uh * Vh);
  } else {                                        // ROW: pre-selected splat
    constexpr int I = U0 >> 1;
    return bcst(su_h[I] * xh[V0]);                // V0==V1 for ROW
  }
}

// 1 MFMA per step (10 per tile)
template<int S>
__device__ __forceinline__ void do_step(int kh,
    const f16x2 (&xh)[8], const f16x2 (&su_h)[8], const f16x2 (&dgh)[4],
    const char* lthp, int base2, int sigh, f32x16& acc)
{
  int va;
  if constexpr (S < 8) va = base2 + ((S ^ sigh) << 5);
  else                 va = base2 + 256 + (((S - 8) ^ (sigh & 1)) << 5);
  int4v thv = *(const int4v*)(lthp + va);
  int4v hh = { dualphi_h<S*4+0>(kh, xh, su_h, dgh),
               dualphi_h<S*4+1>(kh, xh, su_h, dgh),
               dualphi_h<S*4+2>(kh, xh, su_h, dgh),
               dualphi_h<S*4+3>(kh, xh, su_h, dgh) };
  acc = __builtin_amdgcn_mfma_f32_32x32x16_f16(
      __builtin_bit_cast(f16x8, thv), __builtin_bit_cast(f16x8, hh), acc, 0, 0, 0);
}

template<int... Ss>
__device__ __forceinline__ void all_steps(std::integer_sequence<int, Ss...>,
    int kh, const f16x2 (&xh)[8], const f16x2 (&su_h)[8], const f16x2 (&dgh)[4],
    const char* lthp, int base2, int sigh, f32x16& acc)
{
  (do_step<Ss>(kh, xh, su_h, dgh, lthp, base2, sigh, acc), ...);
}

// per-tile pipeline; x -> fp16 via RNE (scalar cvt) since no lo-correction
__device__ __forceinline__ void process_tile(
    const float4 (&xv)[4], int t, int lane, int p, int kh,
    const char* lthp, int base2, int sigh, float* __restrict__ out)
{
  float xs[16];
  xs[0]=xv[0].x; xs[1]=xv[0].y; xs[2]=xv[0].z; xs[3]=xv[0].w;
  xs[4]=xv[1].x; xs[5]=xv[1].y; xs[6]=xv[1].z; xs[7]=xv[1].w;
  xs[8]=xv[2].x; xs[9]=xv[2].y; xs[10]=xv[2].z; xs[11]=xv[2].w;
  xs[12]=xv[3].x; xs[13]=xv[3].y; xs[14]=xv[3].z; xs[15]=xv[3].w;

  f16x2 xh[8];
  #pragma unroll
  for (int i = 0; i < 8; ++i)
    xh[i] = f16x2{(_Float16)xs[2*i], (_Float16)xs[2*i+1]};   // RNE

  f16x2 su_h[8];
  #pragma unroll
  for (int i = 0; i < 8; ++i) {
    f16x2 lo = __builtin_shufflevector(xh[i], xh[i], 0, 0);
    f16x2 hi = __builtin_shufflevector(xh[i], xh[i], 1, 1);
    su_h[i] = fint(kh ? bcst(hi) : bcst(lo));
  }
  f16x2 dgh[4];
  #pragma unroll
  for (int s = 0; s < 4; ++s)
    dgh[s] = __builtin_shufflevector(xh[2*s], xh[2*s+1], 1, 3);

  f32x16 acc;
  #pragma unroll
  for (int i = 0; i < 16; ++i) acc[i] = 0.f;

  all_steps(std::make_integer_sequence<int, NSTEPS>{}, kh, xh, su_h, dgh,
            lthp, base2, sigh, acc);

  float e[16];
  #pragma unroll
  for (int i = 0; i < 16; ++i)
    e[i] = __builtin_amdgcn_exp2f(acc[i]);     // lc folded via slots 148/149
  float a0 = (e[0] + e[1]) + (e[2] + e[3]);
  float a1 = (e[4] + e[5]) + (e[6] + e[7]);
  float a2 = (e[8] + e[9]) + (e[10] + e[11]);
  float a3 = (e[12] + e[13]) + (e[14] + e[15]);
  float ss = (a0 + a1) + (a2 + a3);
  ss += __shfl_xor(ss, 32);
  if (lane < 32) out[(size_t)t * 32 + p] = ss;
}

// ---------------- density kernel: 2 tiles/wave via unroll-1 loop ----------------
// Round-18 best configuration (16.96us). r19 falsified the block-count
// hypothesis (512 blocks was worse); remaining ~11us is per-dispatch
// launch/replay constants + cold-memory first-touch — not reachable from
// kernel source within this harness.
__global__ __launch_bounds__(256) void gm_mfma_kernel(
    const float* __restrict__ x,
    const char*  __restrict__ thimg,
    float* __restrict__ out)
{
  __shared__ __align__(16) char lth[IMG_BYTES];
  const int tid = threadIdx.x;
  const int lane = tid & 63;
  const int p = lane & 31;
  const int kh = lane >> 5;
  const int t0 = (blockIdx.x * 4 + (tid >> 6)) * 2;   // 2 tiles per wave

  // issue both tiles' x loads first (latency hides under staging+barrier)
  const float4* xp0 = (const float4*)(x + ((size_t)t0 * 32 + p) * D);
  const float4* xp1 = (const float4*)(x + ((size_t)(t0 + 1) * 32 + p) * D);
  float4 cur[4], nxt[4];
  #pragma unroll
  for (int i = 0; i < 4; ++i) { cur[i] = xp0[i]; nxt[i] = xp1[i]; }

  // stage theta image -> LDS, pure linear copy (pre-swizzled by prep)
  for (int i = tid; i < IMG_BYTES / 16; i += 256) {
    int4v v = *(const int4v*)(thimg + i * 16);
    *(int4v*)(lth + i * 16) = v;
  }
  __syncthreads();

  const int sig = (p & 7) ^ (p >> 3);
  const int base2 = p * LROW + ((kh ^ (sig & 1)) << 4);
  const int sigh = sig >> 1;

  #pragma unroll 1
  for (int tt = 0; tt < 2; ++tt) {
    process_tile(cur, t0 + tt, lane, p, kh, lth, base2, sigh, out);
    #pragma unroll
    for (int i = 0; i < 4; ++i) cur[i] = nxt[i];   // static-index rotation
  }
}

extern "C" void kernel_launch(void* const* d_in, const int* in_sizes, int n_in,
                              void* d_out, int out_size, void* d_ws, size_t ws_size,
                              hipStream_t stream) {
  const float* x        = (const float*)d_in[0];
  const float* m_w      = (const float*)d_in[1];
  const float* l_fac    = (const float*)d_in[2];
  const float* p_logits = (const float*)d_in[3];
  float* out = (float*)d_out;
  char* thimg = (char*)d_ws;   // IMG_BYTES pre-swizzled fp16 theta image

  gm_prep_kernel<<<K, 256, 0, stream>>>(m_w, l_fac, p_logits, thimg);
  gm_mfma_kernel<<<NBLK, 256, 0, stream>>>(x, thimg, out);
}